// Round 5
// baseline (417.263 us; speedup 1.0000x reference)
//
#include <hip/hip_runtime.h>
#include <math.h>

// FilterMLPBlock: y = irfft(rfft(x,axis=S,ortho)*w, ortho) ; out = LN_D(y + x)
// B=4096, S=64, D=256, F=33. Spectral filter == per-channel real circulant:
//   h[s,d] = sum_t k'[d][(s-t)&63] * x[t,d],  k'[d][0] = k[d][0] + 1 (residual folded)
//   k[d][dlt] = (1/64)(wr0 + (-1)^dlt*wr32 + 2*sum_{f=1..31}(wr_f cos - wi_f sin)(2pi f dlt/64))
// (pocketfft c2r drops Im(DC) and Im(Nyquist).)  Then out = LN_D(h)*gamma + beta.
//
// R5 design notes:
//  - R4 post-mortem: traffic ideal (WRITE=262MB) but VGPR_Count=76 (cap ~ 256/arg2):
//    kd[64]+y[64] (~140 live) overflowed into AGPRs -> ~1 v_accvgpr_read per conv
//    FMA -> VALU issue 2.3x the FMA floor (129us vs 55us), dur stuck ~280us.
//  - Fix: s-split across 2 threads. 512-thread block, thread=(d, half): y[32] +
//    rotated kd[64] + temps ~ 110 live < 128 cap at launch_bounds(512,2).
//    Rotation kd[i]=k[(s0+i)&63][d] keeps all conv indices compile-time:
//    row(s0+j) needs k[(s0+j-t)&63] == kd[(j-t)&63].
//  - Everything macro-expanded (no reliance on unroll heuristics; rule #20).
//  - x streamed straight from global (each element read by 2 threads; 2nd is
//    L1/L2-hit). LDS only for bf16 h-tile + LN partials (~37.6KB, 2 blocks/CU).

#define S_ 64
#define D_ 256
#define TS 258   // ushort row stride: dword stride 129 (odd) -> conflict-free

#define REP4(M, B)  M(B) M((B)+1) M((B)+2) M((B)+3)
#define REP16(M, B) REP4(M, B) REP4(M, (B)+4) REP4(M, (B)+8) REP4(M, (B)+12)
#define REP32(M)    REP16(M, 0) REP16(M, 16)
#define REP64(M)    REP16(M, 0) REP16(M, 16) REP16(M, 32) REP16(M, 48)

__global__ void precompute_k_kernel(const float* __restrict__ cw,
                                    float* __restrict__ k) {
    const int d   = threadIdx.x;   // 0..255
    const int dlt = blockIdx.x;    // 0..63
    // cw layout: [f][d][2] (re, im)
    float acc = cw[(0 * D_ + d) * 2 + 0];                        // wr[0,d]
    acc += ((dlt & 1) ? -1.f : 1.f) * cw[(32 * D_ + d) * 2 + 0]; // wr[32,d]*(-1)^dlt
    const float step = 6.28318530717958647692f / 64.f;
    #pragma unroll
    for (int f = 1; f <= 31; ++f) {
        int m = (f * dlt) & 63;            // exact arg reduction (period 64)
        float th = step * (float)m;
        float sn, cs;
        sincosf(th, &sn, &cs);
        float wr = cw[(f * D_ + d) * 2 + 0];
        float wi = cw[(f * D_ + d) * 2 + 1];
        acc += 2.f * (wr * cs - wi * sn);
    }
    // residual folded in: +1 on the zero-delta tap
    k[dlt * D_ + d] = acc * (1.f / 64.f) + ((dlt == 0) ? 1.f : 0.f);
}

__global__ __launch_bounds__(512, 2)
void filter_ln_kernel(const float* __restrict__ x,
                      const float* __restrict__ k,
                      const float* __restrict__ gamma,
                      const float* __restrict__ beta,
                      float* __restrict__ out) {
    __shared__ unsigned short hs2[S_ * TS];   // h tile (bf16) for LN reduction
    __shared__ float psum[512];               // 8 partials x 64 rows
    __shared__ float psumsq[512];
    __shared__ float mr[S_ * 2];              // per-row mean, rstd

    const int tid = threadIdx.x;              // 0..511
    const int d   = tid & 255;                // channel
    const int s0  = (tid >> 8) * 32;          // output-row base (0 or 32)
    const int b   = blockIdx.x;
    const float* __restrict__ xb = x + (size_t)b * (S_ * D_);

    // ---- rotated circulant column: kd[i] = k'[(s0+i)&63][d] (static idx) ----
    float kd[64];
#define KLOAD(I) kd[I] = k[(((I) + s0) & 63) * D_ + d];
    REP64(KLOAD)
#undef KLOAD

    float y[32];
#define YZERO(J) y[J] = 0.f;
    REP32(YZERO)
#undef YZERO

    // ---- conv: stream own x column from global; all indices compile-time ----
#define CONV_STEP(T) { const float xt = xb[(T) * D_ + d]; \
    _Pragma("unroll") \
    for (int j = 0; j < 32; ++j) y[j] = fmaf(kd[(j - (T)) & 63], xt, y[j]); }
    REP64(CONV_STEP)
#undef CONV_STEP

    // ---- write h (bf16 rn) into LDS tile for the cross-thread LN stats ----
#define HWRITE(J) { unsigned hb = __float_as_uint(y[J]); \
    hb = hb + 0x7fffu + ((hb >> 16) & 1u); \
    hs2[((J) + s0) * TS + d] = (unsigned short)(hb >> 16); }
    REP32(HWRITE)
#undef HWRITE
    __syncthreads();

    // ---- LN stats over D per row s (8 partials of 32 elements per row) ----
    {
        const int s = tid & 63, q = tid >> 6;    // q in 0..7 (wave-uniform)
        float s1 = 0.f, s2 = 0.f;
        #pragma unroll
        for (int j = 0; j < 32; ++j) {           // scalars only; LDS runtime idx OK
            float v = __uint_as_float((unsigned)hs2[s * TS + q * 32 + j] << 16);
            s1 += v;
            s2 = fmaf(v, v, s2);
        }
        psum[q * 64 + s]   = s1;
        psumsq[q * 64 + s] = s2;
    }
    __syncthreads();
    if (tid < 64) {
        float s1 = 0.f, s2 = 0.f;
        #pragma unroll
        for (int q = 0; q < 8; ++q) {
            s1 += psum[q * 64 + tid];
            s2 += psumsq[q * 64 + tid];
        }
        float mean = s1 * (1.f / 256.f);
        float var  = s2 * (1.f / 256.f) - mean * mean;
        mr[tid * 2 + 0] = mean;
        mr[tid * 2 + 1] = rsqrtf(var + 1e-12f);
    }
    __syncthreads();

    // ---- normalize fp32 h (still in regs) + affine + coalesced store ----
    const float g  = gamma[d];
    const float bt = beta[d];
    float* __restrict__ ob = out + (size_t)b * (S_ * D_);
#define STORE(J) { const float m = mr[((J) + s0) * 2 + 0], \
                   r = mr[((J) + s0) * 2 + 1]; \
    ob[((J) + s0) * D_ + d] = (y[J] - m) * r * g + bt; }
    REP32(STORE)
#undef STORE
}

extern "C" void kernel_launch(void* const* d_in, const int* in_sizes, int n_in,
                              void* d_out, int out_size, void* d_ws, size_t ws_size,
                              hipStream_t stream) {
    const float* x     = (const float*)d_in[0];
    const float* cw    = (const float*)d_in[1];   // [1,33,256,2]
    const float* gamma = (const float*)d_in[2];
    const float* beta  = (const float*)d_in[3];
    float* out = (float*)d_out;
    float* kk  = (float*)d_ws;                    // 64*256*4 = 64 KB scratch

    precompute_k_kernel<<<64, 256, 0, stream>>>(cw, kk);
    filter_ln_kernel<<<4096, 512, 0, stream>>>(x, kk, gamma, beta, out);
}

// Round 6
// 228.784 us; speedup vs baseline: 1.8238x; 1.8238x over previous
//
#include <hip/hip_runtime.h>
#include <math.h>

// FilterMLPBlock: y = irfft(rfft(x,axis=S,ortho)*w, ortho) ; out = LN_D(y + x)
// B=4096, S=64, D=256. Spectral filter == per-channel real circulant:
//   h[s,d] = sum_t k'[d][(s-t)&63] * x[t,d],  k'[d][0] = k[d][0] + 1 (residual folded)
// Then out = LN_D(h)*gamma + beta.
//
// R6 design notes (post-mortems R1-R5): any thread needing >~90 live VGPRs got
// scratch-spilled (R1/R3) or AGPR-shuffled (R4/R5: VGPR_Count 76/84, one
// v_accvgpr move per FMA, VALUBusy 2-4x the FMA floor). Fix: per-thread state
// = x[32]+y[32] only (~75 regs); circulant taps live in LDS, streamed 2/step
// by a 32-step c-loop whose 32 FMAs have compile-time register indices:
//   y[(i+c)&31] += (i < 32-c ? k0 : k1) * x[i]
// covering taps c+vb and c+32-vb (vb = 32*((sq^tq)&1) handles the s/t-half
// offset via two wave-uniform LDS base pointers -> no divergence, no runtime
// register indexing anywhere (all macro-expanded).
// LDS: hs[64][256] f32 (h tile, also LN exchange) + kdl[64][256] f32 (taps,
// overlaid by LN partials after conv) = 128.6 KB -> 1 block/CU, 16 waves.
// All LDS access patterns are d-contiguous or flat-float4 -> conflict-free
// with the plain layout. Full fp32 end to end.

#define S_ 64
#define D_ 256

// two independent repetition families so they can nest
#define RC4(M,B)  M(B) M((B)+1) M((B)+2) M((B)+3)
#define RC16(M,B) RC4(M,B) RC4(M,(B)+4) RC4(M,(B)+8) RC4(M,(B)+12)
#define RC32(M)   RC16(M,0) RC16(M,16)

#define RI4(M,C,B)  M(B,C) M((B)+1,C) M((B)+2,C) M((B)+3,C)
#define RI16(M,C,B) RI4(M,C,B) RI4(M,C,(B)+4) RI4(M,C,(B)+8) RI4(M,C,(B)+12)
#define RI32(M,C)   RI16(M,C,0) RI16(M,C,16)

__global__ void precompute_k_kernel(const float* __restrict__ cw,
                                    float* __restrict__ k) {
    const int d   = threadIdx.x;   // 0..255
    const int dlt = blockIdx.x;    // 0..63
    // cw layout: [f][d][2] (re, im)
    float acc = cw[(0 * D_ + d) * 2 + 0];                        // wr[0,d]
    acc += ((dlt & 1) ? -1.f : 1.f) * cw[(32 * D_ + d) * 2 + 0]; // wr[32,d]*(-1)^dlt
    const float step = 6.28318530717958647692f / 64.f;
    #pragma unroll
    for (int f = 1; f <= 31; ++f) {
        int m = (f * dlt) & 63;            // exact arg reduction (period 64)
        float th = step * (float)m;
        float sn, cs;
        sincosf(th, &sn, &cs);
        float wr = cw[(f * D_ + d) * 2 + 0];
        float wi = cw[(f * D_ + d) * 2 + 1];
        acc += 2.f * (wr * cs - wi * sn);
    }
    // residual folded in: +1 on the zero-delta tap
    k[dlt * D_ + d] = acc * (1.f / 64.f) + ((dlt == 0) ? 1.f : 0.f);
}

__global__ __launch_bounds__(1024, 1)
void filter_ln_kernel(const float* __restrict__ x,
                      const float* __restrict__ k,
                      const float* __restrict__ gamma,
                      const float* __restrict__ beta,
                      float* __restrict__ out) {
    __shared__ float smem[32768];           // 128 KB
    float* hs  = smem;                      // [64][256] h tile
    float* kdl = smem + 16384;              // [64][256] taps; stats overlay later

    const int tid = threadIdx.x;            // 0..1023
    const int d   = tid & 255;              // channel
    const int sq  = (tid >> 8) & 1;         // s-half
    const int tq  = tid >> 9;               // t-half
    const int b   = blockIdx.x;
    const float* __restrict__ xb = x + (size_t)b * 16384;

    // ---- stage tap table (flat float4, coalesced, conflict-free) ----
    {
        const float4* __restrict__ ksrc = (const float4*)k;
        float4* kdst = (float4*)kdl;
        #pragma unroll
        for (int p = 0; p < 4; ++p)
            kdst[p * 1024 + tid] = ksrc[p * 1024 + tid];
    }

    // ---- own x slice: xr[i] = x[b][tq*32+i][d] (coalesced across wave) ----
    const float* __restrict__ xb2 = xb + tq * 8192 + d;
    float xr[32];
#define XL(I) xr[I] = xb2[(I) * 256];
    RC32(XL)
#undef XL

    float yr[32];
#define YZ(I) yr[I] = 0.f;
    RC32(YZ)
#undef YZ

    __syncthreads();                        // kdl ready

    // ---- conv c-loop: 32 steps x (2 tap reads + 32 static-index FMAs) ----
    // s = sq*32 + j, t = tq*32 + i, j=(i+c)&31:
    //   unwrapped (i<32-c): (s-t)&63 = c + vb      -> kc0
    //   wrapped   (i>=32-c): (s-t)&63 = c + 32 - vb -> kc1
    const int vb = ((sq ^ tq) & 1) * 32;    // wave-uniform
    const float* __restrict__ k0p = kdl + vb * 256 + d;
    const float* __restrict__ k1p = kdl + (32 - vb) * 256 + d;
#define FMA1(I,C) yr[((I)+(C)) & 31] = \
    fmaf(((I) < 32 - (C)) ? kc0 : kc1, xr[I], yr[((I)+(C)) & 31]);
#define CSTEP(C) { const float kc0 = k0p[(C) * 256]; \
                   const float kc1 = k1p[(C) * 256]; \
                   RI32(FMA1, C) }
    RC32(CSTEP)
#undef CSTEP
#undef FMA1

    // ---- merge t-half partials into hs (write then add; d-contig, no LDS
    //      conflicts; disjoint addresses per thread within each phase) ----
    float* hsb = hs + sq * 8192 + d;
    if (tq == 0) {
#define HW0(J) hsb[(J) * 256] = yr[J];
        RC32(HW0)
#undef HW0
    }
    __syncthreads();
    if (tq == 1) {
#define HW1(J) hsb[(J) * 256] += yr[J];
        RC32(HW1)
#undef HW1
    }
    __syncthreads();

    // ---- LN stats: flat float4 chunks (16 floats/thread), then row-reduce.
    //      psum/psq/mr overlay the kdl region (dead after conv). ----
    float* psum = smem + 16384;
    float* psq  = smem + 16384 + 1024;
    float* mr   = smem + 16384 + 2048;      // [64][2] mean, rstd
    {
        const float4* __restrict__ hf = (const float4*)hs + tid * 4;
        float s1 = 0.f, s2 = 0.f;
        #pragma unroll
        for (int j = 0; j < 4; ++j) {
            float4 v = hf[j];
            s1 += v.x + v.y + v.z + v.w;
            s2 = fmaf(v.x, v.x, s2);
            s2 = fmaf(v.y, v.y, s2);
            s2 = fmaf(v.z, v.z, s2);
            s2 = fmaf(v.w, v.w, s2);
        }
        psum[tid] = s1;                     // slot = (row s = tid>>4, q = tid&15)
        psq[tid]  = s2;
    }
    __syncthreads();
    if (tid < 64) {
        float s1 = 0.f, s2 = 0.f;
        #pragma unroll
        for (int j = 0; j < 16; ++j) {
            s1 += psum[tid * 16 + j];
            s2 += psq[tid * 16 + j];
        }
        float mean = s1 * (1.f / 256.f);
        float var  = s2 * (1.f / 256.f) - mean * mean;
        mr[tid * 2 + 0] = mean;
        mr[tid * 2 + 1] = rsqrtf(var + 1e-12f);
    }
    __syncthreads();

    // ---- normalize + affine + store (flat float4, fully coalesced) ----
    float* __restrict__ ob = out + (size_t)b * 16384;
    #pragma unroll
    for (int p = 0; p < 4; ++p) {
        const int f  = (p * 1024 + tid) * 4;   // flat elem index
        const int s  = f >> 8;
        const int dd = f & 255;
        float4 v = *(const float4*)(hs + f);
        const float m = mr[s * 2 + 0];
        const float r = mr[s * 2 + 1];
        const float4 g4 = *(const float4*)(gamma + dd);
        const float4 b4 = *(const float4*)(beta + dd);
        float4 o;
        o.x = (v.x - m) * r * g4.x + b4.x;
        o.y = (v.y - m) * r * g4.y + b4.y;
        o.z = (v.z - m) * r * g4.z + b4.z;
        o.w = (v.w - m) * r * g4.w + b4.w;
        *(float4*)(ob + f) = o;
    }
}

extern "C" void kernel_launch(void* const* d_in, const int* in_sizes, int n_in,
                              void* d_out, int out_size, void* d_ws, size_t ws_size,
                              hipStream_t stream) {
    const float* x     = (const float*)d_in[0];
    const float* cw    = (const float*)d_in[1];   // [1,33,256,2]
    const float* gamma = (const float*)d_in[2];
    const float* beta  = (const float*)d_in[3];
    float* outp = (float*)d_out;
    float* kk   = (float*)d_ws;                   // 64*256*4 = 64 KB scratch

    precompute_k_kernel<<<64, 256, 0, stream>>>(cw, kk);
    filter_ln_kernel<<<4096, 1024, 0, stream>>>(x, kk, gamma, beta, outp);
}